// Round 11
// baseline (469.239 us; speedup 1.0000x reference)
//
#include <hip/hip_runtime.h>
#include <float.h>

typedef _Float16 half8 __attribute__((ext_vector_type(8)));
typedef float f32x4 __attribute__((ext_vector_type(4)));

#define NROWS 32768
#define D 64
#define K 1024
#define L 4
#define BROWS 64   /* rows/block: 512 blocks = 2/CU -- the L2-friendly footprint */
#define PAD 68     /* resid LDS row stride in floats */
#define NGRP 8     /* code groups: 16 waves = 2 row-groups x 8 code-groups */

// ---------------------------------------------------------------------------
// Prep: from emb [D,K,L] fp32 build, per layer l:
//   embT  fp32 [L][K][D]  (exact codes for residual update)
//   ee    fp32 [L][K]     (||e||^2)
//   cbh   f16  [L][K][D]  (hi part)
//   cbl2  f16  [L][K][D]  (lo part * 4096 -- keeps lo in f16 normal range)
// ---------------------------------------------------------------------------
__global__ __launch_bounds__(64) void rvq_prep(const float* __restrict__ emb,
                                               float* __restrict__ embT,
                                               float* __restrict__ ee,
                                               _Float16* __restrict__ cbh,
                                               _Float16* __restrict__ cbl2) {
    const int kl = blockIdx.x * 64 + threadIdx.x;  // kl = k*4 + l
    const int l = kl & 3;
    const int k = kl >> 2;
    alignas(16) float v[D];
    alignas(16) _Float16 h[D];
    alignas(16) _Float16 lo[D];
    float s = 0.f;
#pragma unroll
    for (int d = 0; d < D; ++d) {
        float e = emb[d * (K * L) + kl];  // lane-coalesced over kl
        v[d] = e;
        s = fmaf(e, e, s);
    }
#pragma unroll
    for (int d = 0; d < D; ++d) {
        _Float16 hh = (_Float16)v[d];
        h[d] = hh;
        lo[d] = (_Float16)((v[d] - (float)hh) * 4096.f);
    }
    float4* dT = (float4*)(embT + ((size_t)l * K + k) * D);
#pragma unroll
    for (int j = 0; j < D / 4; ++j) dT[j] = ((const float4*)v)[j];
    float4* dH = (float4*)(cbh + ((size_t)l * K + k) * D);
    float4* dL = (float4*)(cbl2 + ((size_t)l * K + k) * D);
#pragma unroll
    for (int j = 0; j < D / 8; ++j) {  // 64 halfs = 8 float4
        dH[j] = ((const float4*)h)[j];
        dL[j] = ((const float4*)lo)[j];
    }
    ee[l * K + k] = s;
}

// ---------------------------------------------------------------------------
// Main: block = 64 rows, 1024 threads = 16 waves = 2 row-groups (mg, 32 rows)
// x 8 code-groups (ng, 128 codes).  Round-10 evidence: 8-wave blocks at 512
// blocks = 16 waves/CU (44% occ) are latency-bound at 37% issue duty (load
// latency ~250cyc vs 138cyc work/step; compiler sinks prefetches - VGPR
// stayed 64).  Fix: 16-wave blocks keep the SAME 512-block L2 footprint
// (round-7: more blocks => 114MB fetch, thrash) but give 32 waves/CU =
// 8 waves/SIMD TLP.  launch_bounds(1024,8) pins VGPR<=64 (current use: 64).
// Per-row candidate order identical -> absmax must stay 9.765625e-4.
// ---------------------------------------------------------------------------
__global__ __launch_bounds__(1024, 8) void rvq_main(const float* __restrict__ x,
                                                    const float* __restrict__ embT,
                                                    const float* __restrict__ ee,
                                                    const _Float16* __restrict__ cbh,
                                                    const _Float16* __restrict__ cbl2,
                                                    float* __restrict__ out) {
    __shared__ float s_res[BROWS * PAD];    // 17408 B
    __shared__ float s_rr[BROWS];
    __shared__ float s_ee[K];               // 4 KB, current layer
    __shared__ float s_bd[NGRP][BROWS];     // 2 KB
    __shared__ int s_bi[NGRP][BROWS];       // 2 KB
    __shared__ int s_widx[BROWS];

    const int tid = threadIdx.x;
    const int lane = tid & 63;
    const int wave = tid >> 6;
    const int mg = wave >> 3;   // 0..1  row group (32 rows)
    const int ng = wave & 7;    // 0..7  code group (128 codes = 8 steps of 16)
    const int c0 = lane & 15;   // MFMA col class / A row
    const int g4 = lane >> 4;   // MFMA k-group / row-subgroup

    const int rowbase = blockIdx.x * BROWS;
    const int urow = tid >> 4;        // update/IO: row 0..63 (16 thr/row)
    const int ud0 = (tid & 15) * 4;   // update/IO: dim base (one float4)

    // ---- init: x -> s_res, fused rr ----
    {
        const float4 a = *(const float4*)(x + (size_t)(rowbase + urow) * D + ud0);
        *(float4*)(s_res + urow * PAD + ud0) = a;
        float ss = a.x * a.x;
        ss = fmaf(a.y, a.y, ss); ss = fmaf(a.z, a.z, ss); ss = fmaf(a.w, a.w, ss);
        ss += __shfl_xor(ss, 1);
        ss += __shfl_xor(ss, 2);
        ss += __shfl_xor(ss, 4);
        ss += __shfl_xor(ss, 8);
        if ((tid & 15) == 0) s_rr[urow] = ss;
    }

// prefetch loads for 16-code step S of this wave's slice
#define LOADB(S, BH0, BH1, BL0, BL1)                              \
    do {                                                          \
        const int cb16_ = ng * 128 + (S)*16;                      \
        const size_t ob_ = (size_t)(cb16_ + c0) * D + g4 * 8;     \
        BH0 = *(const half8*)(cbhL + ob_);                        \
        BH1 = *(const half8*)(cbhL + ob_ + 32);                   \
        BL0 = *(const half8*)(cblL + ob_);                        \
        BL1 = *(const half8*)(cblL + ob_ + 32);                   \
    } while (0)

// compute + argmin for step S using fragments (order matches prior rounds)
#define COMP(S, BH0, BH1, BL0, BL1)                                              \
    do {                                                                         \
        const int cb16_ = ng * 128 + (S)*16;                                     \
        const float eev_ = s_ee[cb16_ + c0];                                     \
        const int idv_ = cb16_ + c0;                                             \
        _Pragma("unroll") for (int mt = 0; mt < 2; ++mt) {                       \
            f32x4 a_ = (f32x4){0.f, 0.f, 0.f, 0.f};                              \
            f32x4 b_ = (f32x4){0.f, 0.f, 0.f, 0.f};                              \
            a_ = __builtin_amdgcn_mfma_f32_16x16x32_f16(Ah[mt][0], BH0, a_, 0, 0, 0); \
            a_ = __builtin_amdgcn_mfma_f32_16x16x32_f16(Al[mt][0], BH0, a_, 0, 0, 0); \
            b_ = __builtin_amdgcn_mfma_f32_16x16x32_f16(Ah[mt][0], BL0, b_, 0, 0, 0); \
            a_ = __builtin_amdgcn_mfma_f32_16x16x32_f16(Ah[mt][1], BH1, a_, 0, 0, 0); \
            a_ = __builtin_amdgcn_mfma_f32_16x16x32_f16(Al[mt][1], BH1, a_, 0, 0, 0); \
            b_ = __builtin_amdgcn_mfma_f32_16x16x32_f16(Ah[mt][1], BL1, b_, 0, 0, 0); \
            _Pragma("unroll") for (int j = 0; j < 4; ++j) {                      \
                float t_ = rrv[mt][j] + eev_;                                    \
                float sd_ = fmaf(b_[j], 2.44140625e-4f, a_[j]);                  \
                float dd_ = fmaf(-2.f, sd_, t_);                                 \
                bool c_ = dd_ < best[mt][j];                                     \
                best[mt][j] = c_ ? dd_ : best[mt][j];                            \
                bidx[mt][j] = c_ ? idv_ : bidx[mt][j];                           \
            }                                                                    \
        }                                                                        \
    } while (0)

    for (int l = 0; l < L; ++l) {
        __syncthreads();  // resid+rr ready; prior epilogue done with s_ee
        s_ee[tid] = ee[l * K + tid];
        __syncthreads();

        // per-lane rr for the 8 (mt,j) rows this lane's accs cover
        float rrv[2][4];
#pragma unroll
        for (int mt = 0; mt < 2; ++mt)
#pragma unroll
            for (int j = 0; j < 4; ++j)
                rrv[mt][j] = s_rr[mg * 32 + mt * 16 + g4 * 4 + j];

        // A fragments (residual rows), f16 hi/lo
        half8 Ah[2][2], Al[2][2];  // [mt][kstep]
#pragma unroll
        for (int mt = 0; mt < 2; ++mt)
#pragma unroll
            for (int ks = 0; ks < 2; ++ks) {
                const float* src = s_res + (mg * 32 + mt * 16 + c0) * PAD + ks * 32 + g4 * 8;
                float4 p = ((const float4*)src)[0];
                float4 q = ((const float4*)src)[1];
                float vv[8] = {p.x, p.y, p.z, p.w, q.x, q.y, q.z, q.w};
                half8 hh, ll;
#pragma unroll
                for (int e = 0; e < 8; ++e) {
                    _Float16 t = (_Float16)vv[e];
                    hh[e] = t;
                    ll[e] = (_Float16)(vv[e] - (float)t);
                }
                Ah[mt][ks] = hh;
                Al[mt][ks] = ll;
            }

        float best[2][4];
        int bidx[2][4];
#pragma unroll
        for (int mt = 0; mt < 2; ++mt)
#pragma unroll
            for (int j = 0; j < 4; ++j) { best[mt][j] = FLT_MAX; bidx[mt][j] = 0; }

        const _Float16* cbhL = cbh + (size_t)l * K * D;
        const _Float16* cblL = cbl2 + (size_t)l * K * D;

        // --- 8-step loop, ping-pong register buffers ---
        half8 pA_h0, pA_h1, pA_l0, pA_l1;  // buffer A
        half8 pB_h0, pB_h1, pB_l0, pB_l1;  // buffer B
        LOADB(0, pA_h0, pA_h1, pA_l0, pA_l1);
#pragma unroll 1
        for (int sp = 0; sp < 4; ++sp) {
            const int s0 = sp * 2;
            LOADB(s0 + 1, pB_h0, pB_h1, pB_l0, pB_l1);   // prefetch odd step
            COMP(s0, pA_h0, pA_h1, pA_l0, pA_l1);        // compute even step
            const int s2 = (s0 + 2 < 8) ? s0 + 2 : 0;    // tail: redundant, unused
            LOADB(s2, pA_h0, pA_h1, pA_l0, pA_l1);       // prefetch next even
            COMP(s0 + 1, pB_h0, pB_h1, pB_l0, pB_l1);    // compute odd step
        }

        // intra-wave argmin across the 16 col-classes (per row), idx tie-break
#pragma unroll
        for (int mt = 0; mt < 2; ++mt)
#pragma unroll
            for (int j = 0; j < 4; ++j) {
                float d1 = best[mt][j];
                int i1 = bidx[mt][j];
#pragma unroll
                for (int m = 1; m <= 8; m <<= 1) {
                    float d2 = __shfl_xor(d1, m);
                    int i2 = __shfl_xor(i1, m);
                    if (d2 < d1 || (d2 == d1 && i2 < i1)) { d1 = d2; i1 = i2; }
                }
                if (c0 == 0) {
                    int row = mg * 32 + mt * 16 + g4 * 4 + j;
                    s_bd[ng][row] = d1;
                    s_bi[ng][row] = i1;
                }
            }
        __syncthreads();
        if (tid < BROWS) {
            float gb = s_bd[0][tid];
            int gi = s_bi[0][tid];
#pragma unroll
            for (int n = 1; n < NGRP; ++n) {
                float dn = s_bd[n][tid];  // ng ascending = code ranges ascending
                int in = s_bi[n][tid];
                if (dn < gb) { gb = dn; gi = in; }
            }
            s_widx[tid] = gi;
        }
        __syncthreads();

        // residual update (exact fp32) + fused rr for next layer
        {
            const int w = s_widx[urow];
            const float4 u = *(const float4*)(embT + ((size_t)l * K + w) * D + ud0);
            float* rp = s_res + urow * PAD + ud0;
            float4 r0 = *(float4*)rp;
            r0.x -= u.x; r0.y -= u.y; r0.z -= u.z; r0.w -= u.w;
            *(float4*)rp = r0;
            float ss = r0.x * r0.x;
            ss = fmaf(r0.y, r0.y, ss); ss = fmaf(r0.z, r0.z, ss); ss = fmaf(r0.w, r0.w, ss);
            ss += __shfl_xor(ss, 1);
            ss += __shfl_xor(ss, 2);
            ss += __shfl_xor(ss, 4);
            ss += __shfl_xor(ss, 8);
            if ((tid & 15) == 0) s_rr[urow] = ss;
        }
    }

    // out = x - residual_final (same thread wrote these s_res bytes: no barrier)
    {
        const float4 a = *(const float4*)(x + (size_t)(rowbase + urow) * D + ud0);
        const float4 r0 = *(const float4*)(s_res + urow * PAD + ud0);
        float4 o0;
        o0.x = a.x - r0.x; o0.y = a.y - r0.y; o0.z = a.z - r0.z; o0.w = a.w - r0.w;
        *(float4*)(out + (size_t)(rowbase + urow) * D + ud0) = o0;
    }
#undef LOADB
#undef COMP
}

extern "C" void kernel_launch(void* const* d_in, const int* in_sizes, int n_in,
                              void* d_out, int out_size, void* d_ws, size_t ws_size,
                              hipStream_t stream) {
    const float* x = (const float*)d_in[0];    // [32,32,32,64] fp32
    const float* emb = (const float*)d_in[1];  // [64,1024,4] fp32
    float* out = (float*)d_out;

    char* ws = (char*)d_ws;
    float* embT = (float*)ws;                                  // 1 MB
    float* ee = (float*)(ws + (size_t)L * K * D * 4);          // 16 KB
    _Float16* cbh = (_Float16*)(ws + (size_t)L * K * D * 4 + L * K * 4);
    _Float16* cbl2 = (_Float16*)(ws + (size_t)L * K * D * 4 + L * K * 4 + (size_t)L * K * D * 2);

    rvq_prep<<<(K * L) / 64, 64, 0, stream>>>(emb, embT, ee, cbh, cbl2);
    rvq_main<<<NROWS / BROWS, 1024, 0, stream>>>(x, embT, ee, cbh, cbl2, out);
}

// Round 13
// 137.883 us; speedup vs baseline: 3.4032x; 3.4032x over previous
//
#include <hip/hip_runtime.h>
#include <float.h>

typedef _Float16 half8 __attribute__((ext_vector_type(8)));
typedef float f32x4 __attribute__((ext_vector_type(4)));

#define NROWS 32768
#define D 64
#define K 1024
#define L 4
#define BROWS 64    /* rows/block: 512 blocks = 2/CU -- the L2-friendly shape */
#define PAD 68      /* resid LDS row stride in floats */
#define CHALF 8192  /* halfs per 64-code chunk (64 codes x 128 halfs = 16KB) */

// ---------------------------------------------------------------------------
// Prep: from emb [D,K,L] fp32 build, per layer l:
//   embT  fp32 [L][K][D]    (exact codes for residual update)
//   ee    fp32 [L][K]       (||e||^2)
//   cbi   f16  [L][K][128]  (interleaved per code: 64 hi halfs | 64 lo*4096)
// ---------------------------------------------------------------------------
__global__ __launch_bounds__(64) void rvq_prep(const float* __restrict__ emb,
                                               float* __restrict__ embT,
                                               float* __restrict__ ee,
                                               _Float16* __restrict__ cbi) {
    const int kl = blockIdx.x * 64 + threadIdx.x;  // kl = k*4 + l
    const int l = kl & 3;
    const int k = kl >> 2;
    alignas(16) float v[D];
    alignas(16) _Float16 h[D];
    alignas(16) _Float16 lo[D];
    float s = 0.f;
#pragma unroll
    for (int d = 0; d < D; ++d) {
        float e = emb[d * (K * L) + kl];  // lane-coalesced over kl
        v[d] = e;
        s = fmaf(e, e, s);
    }
#pragma unroll
    for (int d = 0; d < D; ++d) {
        _Float16 hh = (_Float16)v[d];
        h[d] = hh;
        lo[d] = (_Float16)((v[d] - (float)hh) * 4096.f);
    }
    float4* dT = (float4*)(embT + ((size_t)l * K + k) * D);
#pragma unroll
    for (int j = 0; j < D / 4; ++j) dT[j] = ((const float4*)v)[j];
    float4* dC = (float4*)(cbi + ((size_t)l * K + k) * 128);
#pragma unroll
    for (int j = 0; j < D / 8; ++j) {  // 8 float4 = 64 halfs each region
        dC[j] = ((const float4*)h)[j];       // hi at halfs 0..63
        dC[8 + j] = ((const float4*)lo)[j];  // lo at halfs 64..127
    }
    ee[l * K + k] = s;
}

// ---------------------------------------------------------------------------
// Main: block = 64 rows, 8 waves = 2 row-groups (mg, 32 rows) x 4
// chunk-quarters (nq, 16 codes of each staged 64-code chunk).  Codebook is
// staged cooperatively into double-buffered LDS via async global_load_lds
// (m97 pattern): stage chunk c+1 -> compute chunk c from LDS -> barrier.
// Compiler pipelines the LDS->MFMA hop (counted lgkmcnt) which it does well;
// the global hop is async with no register destination (r10/r12 lesson:
// global->reg prefetches get sunk or need fragile asm).
// LDS read conflicts (256B code rows = 16-way) fixed per rule 21: inverse-
// swizzled GLOBAL source + XOR-swizzled LDS read, granule map
// g = r*16 + (j ^ (r&15)) (bijective per row; ~2 lanes/bank on read = free).
// Per-candidate arithmetic identical to r4/r10; all argmin combines carry
// index tie-breaks -> picks identical -> absmax must stay 9.765625e-4.
// ---------------------------------------------------------------------------
__global__ __launch_bounds__(512, 4) void rvq_main(const float* __restrict__ x,
                                                   const float* __restrict__ embT,
                                                   const float* __restrict__ ee,
                                                   const _Float16* __restrict__ cbi,
                                                   float* __restrict__ out) {
    __shared__ alignas(16) _Float16 s_cb[2][CHALF];  // 32 KB staging
    __shared__ alignas(16) float s_res[BROWS * PAD]; // 17408 B
    __shared__ float s_rr[BROWS];
    __shared__ float s_ee[K];                        // 4 KB
    __shared__ float s_bd[4][BROWS];
    __shared__ int s_bi[4][BROWS];
    __shared__ int s_widx[BROWS];

    const int tid = threadIdx.x;
    const int lane = tid & 63;
    const int wave = tid >> 6;
    const int mg = wave >> 2;  // 0..1  row group (32 rows)
    const int nq = wave & 3;   // 0..3  16-code quarter of each chunk
    const int c0 = lane & 15;  // MFMA col class (code within quarter)
    const int g4 = lane >> 4;  // MFMA k-group / row-subgroup

    const int rowbase = blockIdx.x * BROWS;
    const int urow = tid >> 3;      // update/IO: row 0..63 (8 thr/row)
    const int ud0 = (tid & 7) * 8;  // update/IO: dim base (two float4)

    // LDS half-offsets of this lane's 4 B-fragments (constant per lane):
    // code row r = nq*16 + c0 (r & 15 == c0), fragment granule j = g4 + 4t,
    // swizzled granule = r*16 + (j ^ c0).
    const int hb = (nq * 16 + c0) * 128;
    const int xo0 = hb + (((g4 + 0) ^ c0) * 8);
    const int xo1 = hb + (((g4 + 4) ^ c0) * 8);
    const int xo2 = hb + (((g4 + 8) ^ c0) * 8);
    const int xo3 = hb + (((g4 + 12) ^ c0) * 8);

    // Stage constants (i = 0,1): lane's inverse-swizzled global source offset
    // (halfs within chunk) and the wave-uniform LDS dest offset (halfs).
    int soff0, soff1, dsto0, dsto1;
    {
        int g0 = (wave * 2 + 0) * 64 + lane;   // LDS granule this lane fills
        int r0 = g0 >> 4;
        soff0 = r0 * 128 + (((g0 & 15) ^ (r0 & 15)) * 8);
        dsto0 = (wave * 2 + 0) * 512;
        int g1 = (wave * 2 + 1) * 64 + lane;
        int r1 = g1 >> 4;
        soff1 = r1 * 128 + (((g1 & 15) ^ (r1 & 15)) * 8);
        dsto1 = (wave * 2 + 1) * 512;
    }

#define STAGE(B, C)                                                            \
    do {                                                                       \
        __builtin_amdgcn_global_load_lds(                                      \
            (const __attribute__((address_space(1))) void*)(cbiL +             \
                (size_t)(C) * CHALF + soff0),                                  \
            (__attribute__((address_space(3))) void*)(&s_cb[(B)][dsto0]),      \
            16, 0, 0);                                                         \
        __builtin_amdgcn_global_load_lds(                                      \
            (const __attribute__((address_space(1))) void*)(cbiL +             \
                (size_t)(C) * CHALF + soff1),                                  \
            (__attribute__((address_space(3))) void*)(&s_cb[(B)][dsto1]),      \
            16, 0, 0);                                                         \
    } while (0)

    // ---- init: x -> s_res, fused rr ----
    {
        const float4* xp = (const float4*)(x + (size_t)(rowbase + urow) * D + ud0);
        float4 a = xp[0], b = xp[1];
        float* dst = s_res + urow * PAD + ud0;
        ((float4*)dst)[0] = a;
        ((float4*)dst)[1] = b;
        float ss = a.x * a.x;
        ss = fmaf(a.y, a.y, ss); ss = fmaf(a.z, a.z, ss); ss = fmaf(a.w, a.w, ss);
        ss = fmaf(b.x, b.x, ss); ss = fmaf(b.y, b.y, ss); ss = fmaf(b.z, b.z, ss);
        ss = fmaf(b.w, b.w, ss);
        ss += __shfl_xor(ss, 1);
        ss += __shfl_xor(ss, 2);
        ss += __shfl_xor(ss, 4);
        if ((tid & 7) == 0) s_rr[urow] = ss;
    }

    for (int l = 0; l < L; ++l) {
        __syncthreads();  // s_res/s_rr final; prior layer fully done
        s_ee[tid] = ee[l * K + tid];
        s_ee[tid + 512] = ee[l * K + tid + 512];
        const _Float16* cbiL = cbi + (size_t)l * (K * 128);

        STAGE(0, 0);  // async: chunk 0 flies while we do A-prep

        // per-lane rr for the 8 (mt,j) rows this lane's accs cover
        float rrv[2][4];
#pragma unroll
        for (int mt = 0; mt < 2; ++mt)
#pragma unroll
            for (int j = 0; j < 4; ++j)
                rrv[mt][j] = s_rr[mg * 32 + mt * 16 + g4 * 4 + j];

        // A fragments (residual rows), f16 hi/lo
        half8 Ah[2][2], Al[2][2];  // [mt][kstep]
#pragma unroll
        for (int mt = 0; mt < 2; ++mt)
#pragma unroll
            for (int ks = 0; ks < 2; ++ks) {
                const float* src = s_res + (mg * 32 + mt * 16 + c0) * PAD + ks * 32 + g4 * 8;
                float4 p = ((const float4*)src)[0];
                float4 q = ((const float4*)src)[1];
                float vv[8] = {p.x, p.y, p.z, p.w, q.x, q.y, q.z, q.w};
                half8 hh, ll;
#pragma unroll
                for (int e = 0; e < 8; ++e) {
                    _Float16 t = (_Float16)vv[e];
                    hh[e] = t;
                    ll[e] = (_Float16)(vv[e] - (float)t);
                }
                Ah[mt][ks] = hh;
                Al[mt][ks] = ll;
            }

        float best[2][4];
        int bidx[2][4];
#pragma unroll
        for (int mt = 0; mt < 2; ++mt)
#pragma unroll
            for (int j = 0; j < 4; ++j) { best[mt][j] = FLT_MAX; bidx[mt][j] = 0; }

        __syncthreads();  // s_ee ready AND chunk 0 landed in s_cb[0]

        int buf = 0;
#pragma unroll 1
        for (int c = 0; c < 16; ++c) {
            if (c < 15) STAGE(buf ^ 1, c + 1);  // async next chunk

            // B-fragments from swizzled LDS (ds_read_b128, ~conflict-free)
            const _Float16* bb = &s_cb[buf][0];
            half8 BH0 = *(const half8*)(bb + xo0);
            half8 BH1 = *(const half8*)(bb + xo1);
            half8 BL0 = *(const half8*)(bb + xo2);
            half8 BL1 = *(const half8*)(bb + xo3);

            const int code = c * 64 + nq * 16 + c0;
            const float eev = s_ee[code];
#pragma unroll
            for (int mt = 0; mt < 2; ++mt) {
                f32x4 a_ = (f32x4){0.f, 0.f, 0.f, 0.f};
                f32x4 b_ = (f32x4){0.f, 0.f, 0.f, 0.f};
                a_ = __builtin_amdgcn_mfma_f32_16x16x32_f16(Ah[mt][0], BH0, a_, 0, 0, 0);
                a_ = __builtin_amdgcn_mfma_f32_16x16x32_f16(Al[mt][0], BH0, a_, 0, 0, 0);
                b_ = __builtin_amdgcn_mfma_f32_16x16x32_f16(Ah[mt][0], BL0, b_, 0, 0, 0);
                a_ = __builtin_amdgcn_mfma_f32_16x16x32_f16(Ah[mt][1], BH1, a_, 0, 0, 0);
                a_ = __builtin_amdgcn_mfma_f32_16x16x32_f16(Al[mt][1], BH1, a_, 0, 0, 0);
                b_ = __builtin_amdgcn_mfma_f32_16x16x32_f16(Ah[mt][1], BL1, b_, 0, 0, 0);
#pragma unroll
                for (int j = 0; j < 4; ++j) {
                    float t_ = rrv[mt][j] + eev;
                    float sd_ = fmaf(b_[j], 2.44140625e-4f, a_[j]);
                    float dd_ = fmaf(-2.f, sd_, t_);
                    bool c_ = dd_ < best[mt][j];  // ascending chunks: first idx kept
                    best[mt][j] = c_ ? dd_ : best[mt][j];
                    bidx[mt][j] = c_ ? code : bidx[mt][j];
                }
            }
            __syncthreads();  // readers done with buf; next chunk landed
            buf ^= 1;
        }

        // intra-wave argmin across the 16 col-classes (per row), idx tie-break
#pragma unroll
        for (int mt = 0; mt < 2; ++mt)
#pragma unroll
            for (int j = 0; j < 4; ++j) {
                float d1 = best[mt][j];
                int i1 = bidx[mt][j];
#pragma unroll
                for (int m = 1; m <= 8; m <<= 1) {
                    float d2 = __shfl_xor(d1, m);
                    int i2 = __shfl_xor(i1, m);
                    if (d2 < d1 || (d2 == d1 && i2 < i1)) { d1 = d2; i1 = i2; }
                }
                if (c0 == 0) {
                    int row = mg * 32 + mt * 16 + g4 * 4 + j;
                    s_bd[nq][row] = d1;
                    s_bi[nq][row] = i1;
                }
            }
        __syncthreads();
        if (tid < BROWS) {
            float gb = s_bd[0][tid];
            int gi = s_bi[0][tid];
#pragma unroll
            for (int n = 1; n < 4; ++n) {
                float dn = s_bd[n][tid];
                int in = s_bi[n][tid];
                // nq subsets are code-interleaved: need explicit idx tie-break
                if (dn < gb || (dn == gb && in < gi)) { gb = dn; gi = in; }
            }
            s_widx[tid] = gi;
        }
        __syncthreads();

        // residual update (exact fp32) + fused rr for next layer
        {
            const int w = s_widx[urow];
            const float* up = embT + ((size_t)l * K + w) * D + ud0;
            float4 u0 = ((const float4*)up)[0];
            float4 u1 = ((const float4*)up)[1];
            float* rp = s_res + urow * PAD + ud0;
            float4 r0 = ((float4*)rp)[0];
            float4 r1 = ((float4*)rp)[1];
            r0.x -= u0.x; r0.y -= u0.y; r0.z -= u0.z; r0.w -= u0.w;
            r1.x -= u1.x; r1.y -= u1.y; r1.z -= u1.z; r1.w -= u1.w;
            ((float4*)rp)[0] = r0;
            ((float4*)rp)[1] = r1;
            float ss = r0.x * r0.x;
            ss = fmaf(r0.y, r0.y, ss); ss = fmaf(r0.z, r0.z, ss); ss = fmaf(r0.w, r0.w, ss);
            ss = fmaf(r1.x, r1.x, ss); ss = fmaf(r1.y, r1.y, ss); ss = fmaf(r1.z, r1.z, ss);
            ss = fmaf(r1.w, r1.w, ss);
            ss += __shfl_xor(ss, 1);
            ss += __shfl_xor(ss, 2);
            ss += __shfl_xor(ss, 4);
            if ((tid & 7) == 0) s_rr[urow] = ss;
        }
    }

    // out = x - residual_final (same thread wrote these s_res bytes: no barrier)
    {
        const float4* xp = (const float4*)(x + (size_t)(rowbase + urow) * D + ud0);
        const float* rp = s_res + urow * PAD + ud0;
        float4 a = xp[0], b = xp[1];
        float4 r0 = ((const float4*)rp)[0];
        float4 r1 = ((const float4*)rp)[1];
        float4 o0, o1;
        o0.x = a.x - r0.x; o0.y = a.y - r0.y; o0.z = a.z - r0.z; o0.w = a.w - r0.w;
        o1.x = b.x - r1.x; o1.y = b.y - r1.y; o1.z = b.z - r1.z; o1.w = b.w - r1.w;
        float4* op = (float4*)(out + (size_t)(rowbase + urow) * D + ud0);
        op[0] = o0;
        op[1] = o1;
    }
#undef STAGE
}

extern "C" void kernel_launch(void* const* d_in, const int* in_sizes, int n_in,
                              void* d_out, int out_size, void* d_ws, size_t ws_size,
                              hipStream_t stream) {
    const float* x = (const float*)d_in[0];    // [32,32,32,64] fp32
    const float* emb = (const float*)d_in[1];  // [64,1024,4] fp32
    float* out = (float*)d_out;

    char* ws = (char*)d_ws;
    float* embT = (float*)ws;                                             // 1 MB
    float* ee = (float*)(ws + (size_t)L * K * D * 4);                     // 16 KB
    _Float16* cbi = (_Float16*)(ws + (size_t)L * K * D * 4 + L * K * 4);  // 1 MB

    rvq_prep<<<(K * L) / 64, 64, 0, stream>>>(emb, embT, ee, cbi);
    rvq_main<<<NROWS / BROWS, 512, 0, stream>>>(x, embT, ee, cbi, out);
}